// Round 1
// baseline (340.243 us; speedup 1.0000x reference)
//
#include <hip/hip_runtime.h>
#include <math.h>

#define EPS_AREA 1e-6f
#define EPS_BCE  1e-7f

typedef float v4f __attribute__((ext_vector_type(4)));

// Kernel 1: features_poses[l, j, :, :] = pred_poses_flat[l*3K + j]
// One block per row (row = l*3K+j). inner4 = (fd*fd)/4 float4 stores per row.
// Block 0 / thread 0 additionally zeroes the loss accumulator slot so the
// subsequent loss kernel (same stream, ordered) can atomicAdd into it.
__global__ __launch_bounds__(256) void broadcast_kernel(
    const float* __restrict__ pred, float* __restrict__ out,
    int inner4, int inner_rem, float* __restrict__ loss_slot)
{
    if (blockIdx.x == 0 && threadIdx.x == 0) *loss_slot = 0.0f;

    const int row = blockIdx.x;              // uniform -> scalar load of value
    const float v = pred[row];
    v4f val;
    val.x = v; val.y = v; val.z = v; val.w = v;

    const long inner = (long)inner4 * 4 + inner_rem;
    v4f* dst = (v4f*)(out + (size_t)row * inner);
    for (int i = threadIdx.x; i < inner4; i += blockDim.x) {
        __builtin_nontemporal_store(val, &dst[i]);
    }
    // generic tail (not taken for fd=56: 3136 % 4 == 0)
    if (inner_rem && threadIdx.x < (unsigned)inner_rem) {
        out[(size_t)row * inner + (size_t)inner4 * 4 + threadIdx.x] = v;
    }
}

// Kernel 2: loss = sum_{l,lp} ious[l,lp] * (feedback_loss[l,lp] + bce[l,lp])
// One block per l; 64 threads = 1 wave; lane = lp.
__global__ __launch_bounds__(64) void loss_kernel(
    const float* __restrict__ pred_poses,     // (L,K,3)
    const float* __restrict__ target_poses,   // (Lp,K,3)
    const float* __restrict__ pred_feedbacks, // (L,)
    const float* __restrict__ ious,           // (L,Lp)
    const float* __restrict__ target_areas,   // (Lp,)
    float* __restrict__ loss_out,
    int Lp, int K)
{
    extern __shared__ float sm[];             // px[K], py[K], lpv[K], l1m[K]
    float* px  = sm;
    float* py  = sm + K;
    float* lpv = sm + 2 * K;
    float* l1m = sm + 3 * K;

    const int l   = blockIdx.x;
    const int tid = threadIdx.x;

    if (tid < K) {
        const float* p = pred_poses + ((size_t)l * K + tid) * 3;
        px[tid] = p[0];
        py[tid] = p[1];
        float pv = fminf(fmaxf(p[2], EPS_BCE), 1.0f - EPS_BCE);
        lpv[tid] = logf(pv);
        l1m[tid] = logf(1.0f - pv);
    }
    __syncthreads();

    float partial = 0.0f;
    const int lp = tid;
    if (lp < Lp) {
        const float  invDen = 1.0f / (2.0f * target_areas[lp] + EPS_AREA);
        const float* t = target_poses + (size_t)lp * K * 3;
        float sumExp = 0.0f;
        float sBce   = 0.0f;
        for (int k = 0; k < K; ++k) {
            float tx = t[3 * k + 0];
            float ty = t[3 * k + 1];
            float tv = t[3 * k + 2];
            float dx = px[k] - tx;
            float dy = py[k] - ty;
            float d2 = dx * dx + dy * dy;
            sumExp += expf(-d2 * invDen);
            sBce   += tv * lpv[k] + (1.0f - tv) * l1m[k];
        }
        float tf  = sumExp / (float)K;
        float d   = pred_feedbacks[l] - tf;
        float fb  = d * d;
        float bce = -sBce / (float)K;
        partial = ious[(size_t)l * Lp + lp] * (fb + bce);
    }

    // wave-64 butterfly reduce
    for (int off = 32; off > 0; off >>= 1)
        partial += __shfl_down(partial, off, 64);
    if (tid == 0)
        atomicAdd(loss_out, partial);   // device-scope by default on CDNA
}

extern "C" void kernel_launch(void* const* d_in, const int* in_sizes, int n_in,
                              void* d_out, int out_size, void* d_ws, size_t ws_size,
                              hipStream_t stream) {
    const float* pred_poses     = (const float*)d_in[0];  // (L,K,3)
    const float* target_poses   = (const float*)d_in[1];  // (Lp,K,3)
    const float* pred_feedbacks = (const float*)d_in[2];  // (L,)
    const float* ious           = (const float*)d_in[3];  // (L,Lp)
    const float* target_areas   = (const float*)d_in[4];  // (Lp,)
    float* out = (float*)d_out;

    const int L  = in_sizes[2];                 // 512
    const int Lp = in_sizes[4];                 // 64
    const int K  = in_sizes[0] / (3 * L);       // 17

    const long rows  = (long)L * 3 * K;                       // 26112
    const long inner = ((long)out_size - 1) / rows;           // fd*fd = 3136
    const int inner4 = (int)(inner / 4);                      // 784
    const int inner_rem = (int)(inner - (long)inner4 * 4);    // 0

    float* loss_slot = out + ((size_t)out_size - 1);

    broadcast_kernel<<<(int)rows, 256, 0, stream>>>(
        pred_poses, out, inner4, inner_rem, loss_slot);

    const size_t smem = 4 * (size_t)K * sizeof(float);
    loss_kernel<<<L, 64, smem, stream>>>(
        pred_poses, target_poses, pred_feedbacks, ious, target_areas,
        loss_slot, Lp, K);
}